// Round 6
// baseline (323.913 us; speedup 1.0000x reference)
//
#include <hip/hip_runtime.h>

// InnerShiftTriple: bz=4, c=512 (c2=256), h=w=64 (hw=4096), fp32 in/out, int32 mask.
// out = concat([former, latter, shifted]); shifted[i] = former[argmax_j sim(i,j)]
// for masked i over non-masked keys j, cosine sim of "latter" features.
// Argmax invariant to query normalization -> only keys normalized.
// Pass1: NK=8 keys/thread (32B contiguous loads), TQ=16 queries via LDS
// broadcast (DS demand = VALU/8), depth-2 register prefetch of the k-stream.

#define HW 4096
#define C2 256
#define BZd 4
#define TQ 16         // queries per block (LDS broadcast)
#define NK 8          // keys per thread (two float4s, 32B contiguous)
#define BT 256        // slice = BT*NK = 2048 keys
#define KS 2048       // keys per slice
#define NSL 2         // up to 2 slices
#define QT_MAX 256    // HW/TQ

__device__ __forceinline__ unsigned ordf(float f) {
  unsigned u = __float_as_uint(f);
  return (u & 0x80000000u) ? ~u : (u | 0x80000000u);
}

__device__ __forceinline__ unsigned long long shfl_down_u64(unsigned long long v, int off) {
  unsigned lo = (unsigned)v, hi = (unsigned)(v >> 32);
  lo = __shfl_down(lo, off, 64);
  hi = __shfl_down(hi, off, 64);
  return ((unsigned long long)hi << 32) | lo;
}

// --- K1: inv-norm (blocks 0..255, 64 px each) + compaction (blocks 256..259) --
__global__ void prep_kernel(const float* __restrict__ in, const int* __restrict__ mask,
                            float* __restrict__ inv, int* __restrict__ qcnt,
                            int* __restrict__ kcnt, int* __restrict__ qlist,
                            int* __restrict__ klist, int* __restrict__ srcmap) {
  __shared__ int sm[256];
  int bid = blockIdx.x, t = threadIdx.x;
  if (bid < 256) {
    float* smf = (float*)sm;
    int b = bid >> 6;
    int px0 = (bid & 63) * 64;
    int px = t & 63, cg = t >> 6;           // 4 channel-groups of 64
    const float* p = in + ((size_t)(b * 512 + C2 + cg * 64)) * HW + px0 + px;
    float ss = 0.f;
#pragma unroll 8
    for (int c = 0; c < 64; ++c) { float v = p[(size_t)c * HW]; ss = fmaf(v, v, ss); }
    smf[cg * 64 + px] = ss;
    __syncthreads();
    if (t < 64) {
      float tot = smf[t] + smf[64 + t] + smf[128 + t] + smf[192 + t];
      inv[b * HW + px0 + t] = 1.0f / (sqrtf(tot) + 1e-8f);
    }
  } else {
    int b = bid - 256;
    const int* m = mask + b * HW;
    int base = t * 16;
    int fl = 0, cq = 0;
#pragma unroll
    for (int i = 0; i < 16; ++i) { int f = (m[base + i] >= 1); fl |= f << i; cq += f; }
    sm[t] = cq; __syncthreads();
    for (int off = 1; off < 256; off <<= 1) {
      int v = (t >= off) ? sm[t - off] : 0;
      __syncthreads(); sm[t] += v; __syncthreads();
    }
    int total = sm[255];
    int qp = sm[t] - cq;
    int kp = base - qp;
    for (int i = 0; i < 16; ++i) {
      int j = base + i;
      if ((fl >> i) & 1) qlist[b * HW + qp++] = j;
      else               klist[b * HW + kp++] = j;
      srcmap[b * HW + j] = -1;
    }
    if (t == 0) { qcnt[b] = total; kcnt[b] = HW - total; }
  }
}

// --- K2: pack keys (normalized) + queries (raw) into GEMM-friendly layouts.
// kpack[((b*C2+c)*NSL+sl)*KS + tt*8 + r] holds key kk = sl*KS + r*256 + tt
// (pass1 thread tt reads its 8 keys/channel as 32B contiguous).
// qpack[(b*C2+c)*HW + jj] holds query jj (0 beyond qcnt).
// Block: 256 packed positions x 32 channels; index/inv loaded once.
__global__ void pack_kernel(const float* __restrict__ in, const float* __restrict__ inv,
                            const int* __restrict__ qcnt, const int* __restrict__ kcnt,
                            const int* __restrict__ qlist, const int* __restrict__ klist,
                            float* __restrict__ kpack, float* __restrict__ qpack) {
  int t = threadIdx.x;
  int jj = blockIdx.x * 256 + t;            // [0,4096)
  int c0 = blockIdx.y * 32;                 // 8 channel-groups of 32
  int b = blockIdx.z;
  int kc = kcnt[b], nq = qcnt[b];
  bool kval = jj < kc, qval = jj < nq;
  int jk = kval ? klist[b * HW + jj] : 0;
  int jq = qval ? qlist[b * HW + jj] : 0;
  float ik = kval ? inv[b * HW + jk] : 0.f;
  int sl = jj >> 11, r = (jj >> 8) & 7, tt = jj & 255;
  float* kdst = kpack + (((size_t)(b * C2 + c0) * NSL + sl) << 11) + tt * 8 + r;
  float* qdst = qpack + ((size_t)(b * C2 + c0)) * HW + jj;
  const float* lat = in + ((size_t)(b * 512 + C2 + c0)) * HW;
#pragma unroll 4
  for (int c = 0; c < 32; ++c) {
    float kv = kval ? lat[(size_t)c * HW + jk] * ik : 0.f;
    float qv = qval ? lat[(size_t)c * HW + jq] : 0.f;
    kdst[(size_t)c * (NSL << 11)] = kv;
    qdst[(size_t)c * HW] = qv;
  }
}

// --- K3: fused GEMM + per-slice argmax. 16 queries (LDS) x 2048-key slice. ---
__global__ __launch_bounds__(BT, 2) void argmax_pass1(
    const float* __restrict__ qpack, const float* __restrict__ kpack,
    const int* __restrict__ qcnt, const int* __restrict__ kcnt,
    unsigned long long* __restrict__ partials) {
  int combo = blockIdx.y;
  int b = combo & 3, sl = combo >> 2;
  int qtile = blockIdx.x;
  int nq_tot = qcnt[b], kc = kcnt[b];
  int qstart = qtile * TQ;
  if (qstart >= nq_tot || (sl << 11) >= kc) return;
  int t = threadIdx.x;

  __shared__ float qt_s[C2][TQ];   // 16 KB
  {
    const float* qb = qpack + ((size_t)b * C2) * HW + qstart;
#pragma unroll
    for (int p = 0; p < 4; ++p) {
      int idx = p * 256 + t;                 // [0,1024)
      int c = idx >> 2, g = idx & 3;
      *(float4*)&qt_s[c][g * 4] = *(const float4*)(qb + (size_t)c * HW + g * 4);
    }
  }
  __syncthreads();

  const float* kcol = kpack + (((size_t)(b * C2) * NSL + sl) << 11) + t * NK;
  const int KSTR = NSL << 11;                // floats per channel step

  float acc[NK][TQ];
#pragma unroll
  for (int r = 0; r < NK; ++r)
#pragma unroll
    for (int q = 0; q < TQ; ++q) acc[r][q] = 0.f;

  // depth-2 rotating prefetch of the 32B key packet
  float4 ka0 = *(const float4*)(kcol);
  float4 ka1 = *(const float4*)(kcol + 4);
  float4 kb0 = *(const float4*)(kcol + KSTR);
  float4 kb1 = *(const float4*)(kcol + KSTR + 4);
#pragma unroll 2
  for (int c = 0; c < C2; ++c) {
    float kv[NK] = {ka0.x, ka0.y, ka0.z, ka0.w, ka1.x, ka1.y, ka1.z, ka1.w};
    ka0 = kb0; ka1 = kb1;
    int cp = c + 2; if (cp > C2 - 1) cp = C2 - 1;
    kb0 = *(const float4*)(kcol + (size_t)cp * KSTR);
    kb1 = *(const float4*)(kcol + (size_t)cp * KSTR + 4);
#pragma unroll
    for (int g = 0; g < 4; ++g) {
      float4 f = *(const float4*)&qt_s[c][g * 4];   // broadcast ds_read_b128
      float qv[4] = {f.x, f.y, f.z, f.w};
#pragma unroll
      for (int r = 0; r < NK; ++r) {
        acc[r][g * 4 + 0] = fmaf(kv[r], qv[0], acc[r][g * 4 + 0]);
        acc[r][g * 4 + 1] = fmaf(kv[r], qv[1], acc[r][g * 4 + 1]);
        acc[r][g * 4 + 2] = fmaf(kv[r], qv[2], acc[r][g * 4 + 2]);
        acc[r][g * 4 + 3] = fmaf(kv[r], qv[3], acc[r][g * 4 + 3]);
      }
    }
  }

  // per-q reduction: pack (value, ~kk) and max across block
  __shared__ unsigned long long red[4][TQ];
  int lane = t & 63, wid = t >> 6;
#pragma unroll
  for (int q = 0; q < TQ; ++q) {
    unsigned long long v = 0ull;
#pragma unroll
    for (int r = 0; r < NK; ++r) {
      int kk = (sl << 11) + (r << 8) + t;
      if (kk < kc) {
        unsigned long long pk =
            ((unsigned long long)ordf(acc[r][q]) << 32) | (unsigned)(0xFFFFFFFFu - (unsigned)kk);
        if (pk > v) v = pk;
      }
    }
    for (int off = 32; off >= 1; off >>= 1) {
      unsigned long long o = shfl_down_u64(v, off);
      if (o > v) v = o;
    }
    if (lane == 0) red[wid][q] = v;
  }
  __syncthreads();
  if (t < TQ) {
    unsigned long long v = red[0][t];
#pragma unroll
    for (int w = 1; w < 4; ++w) if (red[w][t] > v) v = red[w][t];
    partials[(((size_t)b * NSL + sl) * QT_MAX + qtile) * TQ + t] = v;
  }
}

// --- K4: reduce slices -> srcmap --------------------------------------------
__global__ void argmax_pass2(const unsigned long long* __restrict__ partials,
                             const int* __restrict__ qcnt, const int* __restrict__ kcnt,
                             const int* __restrict__ qlist, const int* __restrict__ klist,
                             int* __restrict__ srcmap) {
  int idx = blockIdx.x * 256 + threadIdx.x;  // [0, 16384)
  int b = idx >> 12, qpos = idx & (HW - 1);
  if (qpos >= qcnt[b]) return;
  int kc = kcnt[b];
  int ns = (kc + KS - 1) >> 11;
  int qtile = qpos >> 4, q = qpos & (TQ - 1);
  unsigned long long v = 0ull;
  for (int s = 0; s < ns; ++s) {
    unsigned long long p = partials[(((size_t)b * NSL + s) * QT_MAX + qtile) * TQ + q];
    if (p > v) v = p;
  }
  if (!v) return;
  int kk = (int)(0xFFFFFFFFu - (unsigned)(v & 0xFFFFFFFFull));
  srcmap[b * HW + qlist[b * HW + qpos]] = klist[b * HW + kk];
}

// --- K5: all outputs: passthrough copy (float4) + shifted gather -------------
__global__ void out_kernel(const float* __restrict__ in, const int* __restrict__ srcmap,
                           float* __restrict__ out) {
  int bid = blockIdx.x;
  if (bid < 8192) {
    size_t idx = (size_t)bid * 256 + threadIdx.x;
    int b = (int)(idx >> 19);
    size_t r = idx & 524287;
    float4 v = ((const float4*)in)[((size_t)b << 19) + r];
    ((float4*)(out + (size_t)b * 768 * HW))[r] = v;
  } else {
    int idx = (bid - 8192) * 256 + threadIdx.x;   // [0, 2^22)
    int j = idx & (HW - 1);
    int c = (idx >> 12) & 255;
    int b = idx >> 20;
    int s = srcmap[b * HW + j];
    float v = (s >= 0) ? in[((size_t)b * 512 + c) * HW + s] : 0.f;
    out[((size_t)b * 768 + 512 + c) * HW + j] = v;
  }
}

extern "C" void kernel_launch(void* const* d_in, const int* in_sizes, int n_in,
                              void* d_out, int out_size, void* d_ws, size_t ws_size,
                              hipStream_t stream) {
  const float* in = (const float*)d_in[0];
  const int* mask = (const int*)d_in[1];
  float* out = (float*)d_out;

  // workspace layout (~34.3 MB)
  unsigned long long* partials = (unsigned long long*)d_ws;             // 4*2*256*16 u64 = 256 KB
  float* kpack = (float*)(partials + (size_t)BZd * NSL * QT_MAX * TQ);  // 16.8 MB
  float* qpack = kpack + (size_t)BZd * C2 * HW;                          // 16.8 MB
  float* inv = qpack + (size_t)BZd * C2 * HW;                            // 64 KB
  int* qlist = (int*)(inv + BZd * HW);                                   // 64 KB
  int* klist = qlist + BZd * HW;                                         // 64 KB
  int* srcmap = klist + BZd * HW;                                        // 64 KB
  int* qcnt = srcmap + BZd * HW;                                         // 16 B
  int* kcnt = qcnt + BZd;                                                // 16 B

  hipLaunchKernelGGL(prep_kernel, dim3(256 + BZd), dim3(256), 0, stream,
                     in, mask, inv, qcnt, kcnt, qlist, klist, srcmap);
  hipLaunchKernelGGL(pack_kernel, dim3(16, 8, BZd), dim3(256), 0, stream,
                     in, inv, qcnt, kcnt, qlist, klist, kpack, qpack);
  hipLaunchKernelGGL(argmax_pass1, dim3(QT_MAX, NSL * BZd), dim3(BT), 0, stream,
                     qpack, kpack, qcnt, kcnt, partials);
  hipLaunchKernelGGL(argmax_pass2, dim3(BZd * HW / 256), dim3(256), 0, stream,
                     partials, qcnt, kcnt, qlist, klist, srcmap);
  hipLaunchKernelGGL(out_kernel, dim3(8192 + 16384), dim3(256), 0, stream,
                     in, srcmap, out);
}

// Round 7
// 297.668 us; speedup vs baseline: 1.0882x; 1.0882x over previous
//
#include <hip/hip_runtime.h>

// InnerShiftTriple: bz=4, c=512 (c2=256), h=w=64 (hw=4096), fp32 in/out, int32 mask.
// out = concat([former, latter, shifted]); shifted[i] = former[argmax_j sim(i,j)]
// for masked i over non-masked keys j, cosine sim of "latter" features.
// Argmax invariant to query normalization -> only keys normalized.
// Pass1 model (per-CU): DS/VALU = 6/NK -> NK=8; waves = (nq/TQ)(kc/64NK)4 >= 4096
// -> TQ=8. 16 waves/CU, acc=64 VGPR, 8KB LDS, keys 32B contiguous per thread.

#define HW 4096
#define C2 256
#define BZd 4
#define TQ 8          // queries per block (LDS broadcast)
#define NK 8          // keys per thread (32B contiguous)
#define BT 256        // slice = BT*NK = 2048 keys
#define KS 2048
#define NSL 2
#define QT_MAX 512    // HW/TQ

__device__ __forceinline__ unsigned ordf(float f) {
  unsigned u = __float_as_uint(f);
  return (u & 0x80000000u) ? ~u : (u | 0x80000000u);
}

__device__ __forceinline__ unsigned long long shfl_down_u64(unsigned long long v, int off) {
  unsigned lo = (unsigned)v, hi = (unsigned)(v >> 32);
  lo = __shfl_down(lo, off, 64);
  hi = __shfl_down(hi, off, 64);
  return ((unsigned long long)hi << 32) | lo;
}

// --- K1: inv-norm (blocks 0..255, 64 px each) + compaction (blocks 256..259) --
__global__ void prep_kernel(const float* __restrict__ in, const int* __restrict__ mask,
                            float* __restrict__ inv, int* __restrict__ qcnt,
                            int* __restrict__ kcnt, int* __restrict__ qlist,
                            int* __restrict__ klist, int* __restrict__ srcmap) {
  __shared__ int sm[256];
  int bid = blockIdx.x, t = threadIdx.x;
  if (bid < 256) {
    float* smf = (float*)sm;
    int b = bid >> 6;
    int px0 = (bid & 63) * 64;
    int px = t & 63, cg = t >> 6;           // 4 channel-groups of 64
    const float* p = in + ((size_t)(b * 512 + C2 + cg * 64)) * HW + px0 + px;
    float ss = 0.f;
#pragma unroll 8
    for (int c = 0; c < 64; ++c) { float v = p[(size_t)c * HW]; ss = fmaf(v, v, ss); }
    smf[cg * 64 + px] = ss;
    __syncthreads();
    if (t < 64) {
      float tot = smf[t] + smf[64 + t] + smf[128 + t] + smf[192 + t];
      inv[b * HW + px0 + t] = 1.0f / (sqrtf(tot) + 1e-8f);
    }
  } else {
    int b = bid - 256;
    const int* m = mask + b * HW;
    int base = t * 16;
    int fl = 0, cq = 0;
#pragma unroll
    for (int i = 0; i < 16; ++i) { int f = (m[base + i] >= 1); fl |= f << i; cq += f; }
    sm[t] = cq; __syncthreads();
    for (int off = 1; off < 256; off <<= 1) {
      int v = (t >= off) ? sm[t - off] : 0;
      __syncthreads(); sm[t] += v; __syncthreads();
    }
    int total = sm[255];
    int qp = sm[t] - cq;
    int kp = base - qp;
    for (int i = 0; i < 16; ++i) {
      int j = base + i;
      if ((fl >> i) & 1) qlist[b * HW + qp++] = j;
      else               klist[b * HW + kp++] = j;
      srcmap[b * HW + j] = -1;
    }
    if (t == 0) { qcnt[b] = total; kcnt[b] = HW - total; }
  }
}

// --- K2: pack keys (normalized) + queries (raw), both [(b*C2+c)*HW + jj]. -----
// jj = packed position (ascending original index); 0-padded past counts.
__global__ void pack_kernel(const float* __restrict__ in, const float* __restrict__ inv,
                            const int* __restrict__ qcnt, const int* __restrict__ kcnt,
                            const int* __restrict__ qlist, const int* __restrict__ klist,
                            float* __restrict__ kpack, float* __restrict__ qpack) {
  int t = threadIdx.x;
  int jj = blockIdx.x * 256 + t;            // [0,4096)
  int c0 = blockIdx.y * 32;                 // 8 channel-groups of 32
  int b = blockIdx.z;
  int kc = kcnt[b], nq = qcnt[b];
  bool kval = jj < kc, qval = jj < nq;
  int jk = kval ? klist[b * HW + jj] : 0;
  int jq = qval ? qlist[b * HW + jj] : 0;
  float ik = kval ? inv[b * HW + jk] : 0.f;
  float* kdst = kpack + ((size_t)(b * C2 + c0)) * HW + jj;
  float* qdst = qpack + ((size_t)(b * C2 + c0)) * HW + jj;
  const float* lat = in + ((size_t)(b * 512 + C2 + c0)) * HW;
#pragma unroll 4
  for (int c = 0; c < 32; ++c) {
    float kv = kval ? lat[(size_t)c * HW + jk] * ik : 0.f;
    float qv = qval ? lat[(size_t)c * HW + jq] : 0.f;
    kdst[(size_t)c * HW] = kv;
    qdst[(size_t)c * HW] = qv;
  }
}

// --- K3: fused GEMM + per-slice argmax. 8 queries (LDS) x 2048-key slice. ----
__global__ __launch_bounds__(BT, 4) void argmax_pass1(
    const float* __restrict__ qpack, const float* __restrict__ kpack,
    const int* __restrict__ qcnt, const int* __restrict__ kcnt,
    unsigned long long* __restrict__ partials) {
  int combo = blockIdx.y;
  int b = combo & 3, sl = combo >> 2;
  int qtile = blockIdx.x;
  int nq_tot = qcnt[b], kc = kcnt[b];
  int qstart = qtile * TQ;
  if (qstart >= nq_tot || (sl << 11) >= kc) return;
  int t = threadIdx.x;

  __shared__ float qt_s[C2][TQ];   // 8 KB
  {
    const float* qb = qpack + ((size_t)b * C2) * HW + qstart;
#pragma unroll
    for (int p = 0; p < 2; ++p) {
      int idx = p * 256 + t;                 // [0,512)
      int c = idx >> 1, g = idx & 1;
      *(float4*)&qt_s[c][g * 4] = *(const float4*)(qb + (size_t)c * HW + g * 4);
    }
  }
  __syncthreads();

  // thread t owns keys kk = sl*2048 + t*8 + r (32B contiguous per channel)
  const float* kcol = kpack + ((size_t)b * C2) * HW + (sl << 11) + t * NK;

  float acc[NK][TQ];
#pragma unroll
  for (int r = 0; r < NK; ++r)
#pragma unroll
    for (int q = 0; q < TQ; ++q) acc[r][q] = 0.f;

  // depth-2 rotating prefetch of the 32B key packet
  float4 ka0 = *(const float4*)(kcol);
  float4 ka1 = *(const float4*)(kcol + 4);
  float4 kb0 = *(const float4*)(kcol + HW);
  float4 kb1 = *(const float4*)(kcol + HW + 4);
#pragma unroll 2
  for (int c = 0; c < C2; ++c) {
    float kv[NK] = {ka0.x, ka0.y, ka0.z, ka0.w, ka1.x, ka1.y, ka1.z, ka1.w};
    ka0 = kb0; ka1 = kb1;
    int cp = c + 2; if (cp > C2 - 1) cp = C2 - 1;
    kb0 = *(const float4*)(kcol + (size_t)cp * HW);
    kb1 = *(const float4*)(kcol + (size_t)cp * HW + 4);
#pragma unroll
    for (int g = 0; g < 2; ++g) {
      float4 f = *(const float4*)&qt_s[c][g * 4];   // broadcast ds_read_b128
      float qv[4] = {f.x, f.y, f.z, f.w};
#pragma unroll
      for (int r = 0; r < NK; ++r) {
        acc[r][g * 4 + 0] = fmaf(kv[r], qv[0], acc[r][g * 4 + 0]);
        acc[r][g * 4 + 1] = fmaf(kv[r], qv[1], acc[r][g * 4 + 1]);
        acc[r][g * 4 + 2] = fmaf(kv[r], qv[2], acc[r][g * 4 + 2]);
        acc[r][g * 4 + 3] = fmaf(kv[r], qv[3], acc[r][g * 4 + 3]);
      }
    }
  }

  // per-q reduction: pack (value, ~kk), max over r in-register, then block
  __shared__ unsigned long long red[4][TQ];
  int lane = t & 63, wid = t >> 6;
  int kk0 = (sl << 11) + t * NK;
#pragma unroll
  for (int q = 0; q < TQ; ++q) {
    unsigned long long v = 0ull;
#pragma unroll
    for (int r = 0; r < NK; ++r) {
      int kk = kk0 + r;
      if (kk < kc) {
        unsigned long long pk =
            ((unsigned long long)ordf(acc[r][q]) << 32) | (unsigned)(0xFFFFFFFFu - (unsigned)kk);
        if (pk > v) v = pk;
      }
    }
    for (int off = 32; off >= 1; off >>= 1) {
      unsigned long long o = shfl_down_u64(v, off);
      if (o > v) v = o;
    }
    if (lane == 0) red[wid][q] = v;
  }
  __syncthreads();
  if (t < TQ) {
    unsigned long long v = red[0][t];
#pragma unroll
    for (int w = 1; w < 4; ++w) if (red[w][t] > v) v = red[w][t];
    partials[(((size_t)b * NSL + sl) * QT_MAX + qtile) * TQ + t] = v;
  }
}

// --- K4: reduce slices -> srcmap --------------------------------------------
__global__ void argmax_pass2(const unsigned long long* __restrict__ partials,
                             const int* __restrict__ qcnt, const int* __restrict__ kcnt,
                             const int* __restrict__ qlist, const int* __restrict__ klist,
                             int* __restrict__ srcmap) {
  int idx = blockIdx.x * 256 + threadIdx.x;  // [0, 16384)
  int b = idx >> 12, qpos = idx & (HW - 1);
  if (qpos >= qcnt[b]) return;
  int kc = kcnt[b];
  int ns = (kc + KS - 1) >> 11;
  int qtile = qpos >> 3, q = qpos & (TQ - 1);
  unsigned long long v = 0ull;
  for (int s = 0; s < ns; ++s) {
    unsigned long long p = partials[(((size_t)b * NSL + s) * QT_MAX + qtile) * TQ + q];
    if (p > v) v = p;
  }
  if (!v) return;
  int kk = (int)(0xFFFFFFFFu - (unsigned)(v & 0xFFFFFFFFull));
  srcmap[b * HW + qlist[b * HW + qpos]] = klist[b * HW + kk];
}

// --- K5: all outputs: passthrough copy (float4) + shifted gather -------------
__global__ void out_kernel(const float* __restrict__ in, const int* __restrict__ srcmap,
                           float* __restrict__ out) {
  int bid = blockIdx.x;
  if (bid < 8192) {
    size_t idx = (size_t)bid * 256 + threadIdx.x;
    int b = (int)(idx >> 19);
    size_t r = idx & 524287;
    float4 v = ((const float4*)in)[((size_t)b << 19) + r];
    ((float4*)(out + (size_t)b * 768 * HW))[r] = v;
  } else {
    int idx = (bid - 8192) * 256 + threadIdx.x;   // [0, 2^22)
    int j = idx & (HW - 1);
    int c = (idx >> 12) & 255;
    int b = idx >> 20;
    int s = srcmap[b * HW + j];
    float v = (s >= 0) ? in[((size_t)b * 512 + c) * HW + s] : 0.f;
    out[((size_t)b * 768 + 512 + c) * HW + j] = v;
  }
}

extern "C" void kernel_launch(void* const* d_in, const int* in_sizes, int n_in,
                              void* d_out, int out_size, void* d_ws, size_t ws_size,
                              hipStream_t stream) {
  const float* in = (const float*)d_in[0];
  const int* mask = (const int*)d_in[1];
  float* out = (float*)d_out;

  // workspace layout (~34.3 MB)
  unsigned long long* partials = (unsigned long long*)d_ws;             // 4*2*512*8 u64 = 256 KB
  float* kpack = (float*)(partials + (size_t)BZd * NSL * QT_MAX * TQ);  // 16.8 MB
  float* qpack = kpack + (size_t)BZd * C2 * HW;                          // 16.8 MB
  float* inv = qpack + (size_t)BZd * C2 * HW;                            // 64 KB
  int* qlist = (int*)(inv + BZd * HW);                                   // 64 KB
  int* klist = qlist + BZd * HW;                                         // 64 KB
  int* srcmap = klist + BZd * HW;                                        // 64 KB
  int* qcnt = srcmap + BZd * HW;                                         // 16 B
  int* kcnt = qcnt + BZd;                                                // 16 B

  hipLaunchKernelGGL(prep_kernel, dim3(256 + BZd), dim3(256), 0, stream,
                     in, mask, inv, qcnt, kcnt, qlist, klist, srcmap);
  hipLaunchKernelGGL(pack_kernel, dim3(16, 8, BZd), dim3(256), 0, stream,
                     in, inv, qcnt, kcnt, qlist, klist, kpack, qpack);
  hipLaunchKernelGGL(argmax_pass1, dim3(QT_MAX, NSL * BZd), dim3(BT), 0, stream,
                     qpack, kpack, qcnt, kcnt, partials);
  hipLaunchKernelGGL(argmax_pass2, dim3(BZd * HW / 256), dim3(256), 0, stream,
                     partials, qcnt, kcnt, qlist, klist, srcmap);
  hipLaunchKernelGGL(out_kernel, dim3(8192 + 16384), dim3(256), 0, stream,
                     in, srcmap, out);
}